// Round 1
// baseline (344.677 us; speedup 1.0000x reference)
//
#include <hip/hip_runtime.h>
#include <math.h>
#include <float.h>

#define NB 4
#define NP 4096   // points (and vertices) per batch
#define NT 8192   // triangles
#define NS 16     // triangle splits
#define TCH (NT/NS) // 512 triangles per split
#define EPSD 1e-12

__device__ __forceinline__ float sigm(float x) { return 1.0f / (1.0f + expf(-x)); }

// ---------------------------------------------------------------------------
// Kernel 1: per-(batch,triangle) precompute. Gathers sigmoid(vertices) for the
// three face corners and stores a 16-float record:
// [ax ay az abx aby abz acx acy acz aa am cc raa rcc rbb rden]
// Constants computed in double; guarded reciprocals mirror the reference's
// sdiv(|d|<1e-12 -> /1) semantics. rden==0 flags a degenerate triangle
// (interior candidate then falls back to |ap|^2, a valid on-triangle distance).
// ---------------------------------------------------------------------------
__global__ __launch_bounds__(256) void prep_kernel(
    const float* __restrict__ verts, const int* __restrict__ faces,
    float* __restrict__ tri)
{
  int idx = blockIdx.x * 256 + threadIdx.x;
  if (idx >= NB * NT) return;
  int b = idx >> 13;          // / NT
  int t = idx & (NT - 1);
  int f0 = faces[3 * t + 0], f1 = faces[3 * t + 1], f2 = faces[3 * t + 2];
  const float* vb = verts + (size_t)b * 3 * NP;
  // pos[b][n][d] = sigmoid(vertices[b][d][n])
  float ax = sigm(vb[f0]), ay = sigm(vb[NP + f0]), az = sigm(vb[2 * NP + f0]);
  float bx = sigm(vb[f1]), by = sigm(vb[NP + f1]), bz = sigm(vb[2 * NP + f1]);
  float cx = sigm(vb[f2]), cy = sigm(vb[NP + f2]), cz = sigm(vb[2 * NP + f2]);
  float abx = bx - ax, aby = by - ay, abz = bz - az;
  float acx = cx - ax, acy = cy - ay, acz = cz - az;
  double aa = (double)abx * abx + (double)aby * aby + (double)abz * abz;
  double am = (double)abx * acx + (double)aby * acy + (double)abz * acz;
  double cc = (double)acx * acx + (double)acy * acy + (double)acz * acz;
  double den = aa * cc - am * am;       // = va+vb+vc (Gram determinant)
  double bb  = aa - 2.0 * am + cc;      // = |bc|^2 = (d4-d3)+(d5-d6)
  float raa  = (fabs(aa)  < EPSD) ? 1.0f : (float)(1.0 / aa);
  float rcc  = (fabs(cc)  < EPSD) ? 1.0f : (float)(1.0 / cc);
  float rbb  = (fabs(bb)  < EPSD) ? 1.0f : (float)(1.0 / bb);
  float rden = (fabs(den) < EPSD) ? 0.0f : (float)(1.0 / den);
  float* r = tri + (size_t)idx * 16;
  r[0] = ax;  r[1] = ay;  r[2] = az;
  r[3] = abx; r[4] = aby; r[5] = abz;
  r[6] = acx; r[7] = acy; r[8] = acz;
  r[9] = (float)aa; r[10] = (float)am; r[11] = (float)cc;
  r[12] = raa; r[13] = rcc; r[14] = rbb; r[15] = rden;
}

// ---------------------------------------------------------------------------
// Kernel 2: the hot loop. One thread = one point; each block covers 256 points
// of one batch against one 512-triangle split. Branchless region selection in
// exactly the reference's override order (interior <- BC <- AC <- AB <- C <- B <- A).
// Squared distances via closed forms:
//   A : apap
//   B : apap - 2 d1 + aa
//   C : apap - 2 d2 + cc
//   AB: apap - (d1/aa) d1          AC: apap - (d2/cc) d2
//   BC: distB - ((d4-d3)/bb)(d4-d3)
//   in: apap - (vb d1 + vc d2)/den
// ---------------------------------------------------------------------------
__global__ __launch_bounds__(256) void dist_kernel(
    const float* __restrict__ tri, const float* __restrict__ pc,
    float* __restrict__ part)
{
  int bid  = blockIdx.x;
  int pblk = bid & 15;
  int s    = (bid >> 4) & 15;
  int b    = bid >> 8;
  int p    = pblk * 256 + threadIdx.x;
  const float* pp = pc + ((size_t)b * NP + p) * 3;
  float px = pp[0], py = pp[1], pz = pp[2];

  const float4* __restrict__ R =
      (const float4*)(tri + (size_t)(b * NT + s * TCH) * 16);
  float mind = FLT_MAX;

  for (int t = 0; t < TCH; ++t) {
    float4 r0 = R[0], r1 = R[1], r2 = R[2], r3 = R[3];
    R += 4;
    float apx = px - r0.x, apy = py - r0.y, apz = pz - r0.z;
    float abx = r0.w, aby = r1.x, abz = r1.y;
    float acx = r1.z, acy = r1.w, acz = r2.x;
    float aa = r2.y, am = r2.z, cc = r2.w;
    float raa = r3.x, rcc = r3.y, rbb = r3.z, rden = r3.w;

    float d1   = abx * apx + aby * apy + abz * apz;
    float d2   = acx * apx + acy * apy + acz * apz;
    float apap = apx * apx + apy * apy + apz * apz;
    float d3 = d1 - aa, d4 = d2 - am, d5 = d1 - am, d6 = d2 - cc;
    float vb = d1 * cc - am * d2;
    float vc = aa * d2 - am * d1;
    float va = d3 * d6 - d5 * d4;
    float d43 = d4 - d3, d56 = d5 - d6;

    float dist  = apap - (vb * d1 + vc * d2) * rden;   // interior
    float distB = apap - 2.0f * d1 + aa;

    bool cBC = (va <= 0.0f) & (d43 >= 0.0f) & (d56 >= 0.0f);
    float tbc = d43 * rbb;
    dist = cBC ? (distB - tbc * d43) : dist;

    bool cAC = (vb <= 0.0f) & (d2 >= 0.0f) & (d6 <= 0.0f);
    dist = cAC ? (apap - (d2 * rcc) * d2) : dist;

    bool cAB = (vc <= 0.0f) & (d1 >= 0.0f) & (d3 <= 0.0f);
    dist = cAB ? (apap - (d1 * raa) * d1) : dist;

    bool cC = (d6 >= 0.0f) & (d56 <= 0.0f);
    dist = cC ? (apap - 2.0f * d2 + cc) : dist;

    bool cB = (d3 >= 0.0f) & (d43 <= 0.0f);
    dist = cB ? distB : dist;

    bool cA = (d1 <= 0.0f) & (d2 <= 0.0f);
    dist = cA ? apap : dist;

    mind = fminf(mind, dist);
  }
  part[((size_t)b * NS + s) * NP + p] = fmaxf(mind, 0.0f);
}

// ---------------------------------------------------------------------------
// Kernel 3: per-batch reduction. One block per batch, 1024 threads: min over
// the NS partials per point, mask from pc, masked sums -> per-batch loss.
// ---------------------------------------------------------------------------
__global__ __launch_bounds__(1024) void reduce_kernel(
    const float* __restrict__ part, const float* __restrict__ pc,
    float* __restrict__ bl)
{
  int b = blockIdx.x, tid = threadIdx.x;
  float sdm = 0.0f, sm = 0.0f;
  for (int p = tid; p < NP; p += 1024) {
    float m = FLT_MAX;
    #pragma unroll
    for (int s = 0; s < NS; ++s)
      m = fminf(m, part[((size_t)b * NS + s) * NP + p]);
    const float* pp = pc + ((size_t)b * NP + p) * 3;
    float x = pp[0], y = pp[1], z = pp[2];
    float msk = ((x != 0.0f) | (y != 0.0f) | (z != 0.0f)) ? 1.0f : 0.0f;
    sdm += m * msk;
    sm  += msk;
  }
  __shared__ float s1[16], s2[16];
  for (int off = 32; off > 0; off >>= 1) {
    sdm += __shfl_down(sdm, off, 64);
    sm  += __shfl_down(sm,  off, 64);
  }
  int wave = tid >> 6, lane = tid & 63;
  if (lane == 0) { s1[wave] = sdm; s2[wave] = sm; }
  __syncthreads();
  if (wave == 0) {
    sdm = (lane < 16) ? s1[lane] : 0.0f;
    sm  = (lane < 16) ? s2[lane] : 0.0f;
    for (int off = 8; off > 0; off >>= 1) {
      sdm += __shfl_down(sdm, off, 64);
      sm  += __shfl_down(sm,  off, 64);
    }
    if (lane == 0) bl[b] = sdm / fmaxf(sm, 1.0f);
  }
}

__global__ void final_kernel(const float* __restrict__ bl, float* __restrict__ out)
{
  if (threadIdx.x == 0 && blockIdx.x == 0)
    out[0] = 0.25f * (bl[0] + bl[1] + bl[2] + bl[3]);
}

extern "C" void kernel_launch(void* const* d_in, const int* in_sizes, int n_in,
                              void* d_out, int out_size, void* d_ws, size_t ws_size,
                              hipStream_t stream) {
  const float* verts = (const float*)d_in[0];   // (4,3,16,16,16) f32
  const float* pc    = (const float*)d_in[1];   // (4,4096,3) f32
  const int*   faces = (const int*)d_in[2];     // (8192,3) i32
  float* out = (float*)d_out;

  float* tri  = (float*)d_ws;                       // NB*NT*16 = 524288 floats (2 MB)
  float* part = tri  + (size_t)NB * NT * 16;        // NB*NS*NP = 262144 floats (1 MB)
  float* bl   = part + (size_t)NB * NS * NP;        // 4 floats

  prep_kernel<<<(NB * NT) / 256, 256, 0, stream>>>(verts, faces, tri);
  dist_kernel<<<NB * NS * 16, 256, 0, stream>>>(tri, pc, part);
  reduce_kernel<<<NB, 1024, 0, stream>>>(part, pc, bl);
  final_kernel<<<1, 64, 0, stream>>>(bl, out);
}

// Round 2
// 225.157 us; speedup vs baseline: 1.5308x; 1.5308x over previous
//
#include <hip/hip_runtime.h>
#include <math.h>
#include <float.h>

#define NB 4
#define NP 4096    // points (and vertices) per batch
#define NT 8192    // triangles
#define NS 32      // triangle splits
#define TCH (NT/NS) // 256 triangles per split
#define TREC 20    // floats per triangle record (5 x float4)
#define EPSD 1e-12

__device__ __forceinline__ float sigm(float x) { return 1.0f / (1.0f + expf(-x)); }

// ---------------------------------------------------------------------------
// Kernel 1: per-(batch,triangle) precompute -> 20-float record:
// [ax ay az abx | aby abz acx acy | acz aa am cc | raa rcc rbb rden | den bb k1 pad]
// Constants in double. den = aa*cc - am^2 (Gram det) is EXACTLY 0 for
// duplicate-index faces -> the strict va>0 inside-test in kernel 2 excludes
// them, falling back to the edge-segment min (exactly right for degenerate
// triangles). k1 = aa - am (for the BC-edge parameter e = d2 - d1 + k1).
// ---------------------------------------------------------------------------
__global__ __launch_bounds__(256) void prep_kernel(
    const float* __restrict__ verts, const int* __restrict__ faces,
    float* __restrict__ tri)
{
  int idx = blockIdx.x * 256 + threadIdx.x;
  if (idx >= NB * NT) return;
  int b = idx >> 13;          // / NT
  int t = idx & (NT - 1);
  int f0 = faces[3 * t + 0], f1 = faces[3 * t + 1], f2 = faces[3 * t + 2];
  const float* vb = verts + (size_t)b * 3 * NP;
  float ax = sigm(vb[f0]), ay = sigm(vb[NP + f0]), az = sigm(vb[2 * NP + f0]);
  float bx = sigm(vb[f1]), by = sigm(vb[NP + f1]), bz = sigm(vb[2 * NP + f1]);
  float cx = sigm(vb[f2]), cy = sigm(vb[NP + f2]), cz = sigm(vb[2 * NP + f2]);
  float abx = bx - ax, aby = by - ay, abz = bz - az;
  float acx = cx - ax, acy = cy - ay, acz = cz - az;
  double aa = (double)abx * abx + (double)aby * aby + (double)abz * abz;
  double am = (double)abx * acx + (double)aby * acy + (double)abz * acz;
  double cc = (double)acx * acx + (double)acy * acy + (double)acz * acz;
  double den = aa * cc - am * am;       // Gram determinant; 0 iff degenerate
  double bb  = aa - 2.0 * am + cc;      // |bc|^2
  float raa  = (fabs(aa)  < EPSD) ? 1.0f : (float)(1.0 / aa);
  float rcc  = (fabs(cc)  < EPSD) ? 1.0f : (float)(1.0 / cc);
  float rbb  = (fabs(bb)  < EPSD) ? 1.0f : (float)(1.0 / bb);
  float rden = (fabs(den) < EPSD) ? 0.0f : (float)(1.0 / den);
  float* r = tri + (size_t)idx * TREC;
  r[0]  = ax;  r[1]  = ay;  r[2]  = az;
  r[3]  = abx; r[4]  = aby; r[5]  = abz;
  r[6]  = acx; r[7]  = acy; r[8]  = acz;
  r[9]  = (float)aa; r[10] = (float)am; r[11] = (float)cc;
  r[12] = raa; r[13] = rcc; r[14] = rbb; r[15] = rden;
  r[16] = (float)den; r[17] = (float)bb; r[18] = (float)(aa - am); r[19] = 0.0f;
}

// ---------------------------------------------------------------------------
// Kernel 2: hot loop. One thread = one point vs one 256-triangle split.
// dist = barycentric-inside ? plane-projection distance
//                           : min over the 3 edge SEGMENTS (v_med3 clamp).
// Segment AB: t=clamp(d1*raa,0,1); d = apap + t*(t*aa - 2*d1). AC analogous.
// Segment BC: e=d2-d1+(aa-am); t=clamp(e*rbb,0,1); d = distB + t*(t*bb - 2e)
// with distB = apap - 2*d1 + aa. Inside: va=den-vb-vc; strict va>0 excludes
// degenerates; d = apap - (vb*d1 + vc*d2)*rden.
// ---------------------------------------------------------------------------
__global__ __launch_bounds__(256) void dist_kernel(
    const float* __restrict__ tri, const float* __restrict__ pc,
    float* __restrict__ part)
{
  int bid  = blockIdx.x;
  int pblk = bid & 15;
  int s    = (bid >> 4) & (NS - 1);
  int b    = bid >> 9;
  int p    = pblk * 256 + threadIdx.x;
  const float* pp = pc + ((size_t)b * NP + p) * 3;
  float px = pp[0], py = pp[1], pz = pp[2];

  const float4* __restrict__ R =
      (const float4*)(tri + (size_t)(b * NT + s * TCH) * TREC);
  float mind = FLT_MAX;

  #pragma unroll 2
  for (int t = 0; t < TCH; ++t) {
    float4 r0 = R[0], r1 = R[1], r2 = R[2], r3 = R[3], r4 = R[4];
    R += 5;
    float apx = px - r0.x, apy = py - r0.y, apz = pz - r0.z;
    float abx = r0.w, aby = r1.x, abz = r1.y;
    float acx = r1.z, acy = r1.w, acz = r2.x;
    float aa = r2.y, am = r2.z, cc = r2.w;
    float raa = r3.x, rcc = r3.y, rbb = r3.z, rden = r3.w;
    float den = r4.x, bb = r4.y, k1 = r4.z;

    float d1   = abx * apx + aby * apy + abz * apz;
    float d2   = acx * apx + acy * apy + acz * apz;
    float apap = apx * apx + apy * apy + apz * apz;

    float vb = d1 * cc - am * d2;
    float vc = aa * d2 - am * d1;
    float va = den - vb - vc;

    // interior (plane projection)
    float di = apap - (vb * d1 + vc * d2) * rden;

    // edge AB
    float tab = fminf(fmaxf(d1 * raa, 0.0f), 1.0f);
    float uab = tab * aa - d1 - d1;
    float dAB = apap + tab * uab;

    // edge AC
    float tac = fminf(fmaxf(d2 * rcc, 0.0f), 1.0f);
    float uac = tac * cc - d2 - d2;
    float dAC = apap + tac * uac;

    // edge BC
    float e   = d2 - d1 + k1;
    float tbc = fminf(fmaxf(e * rbb, 0.0f), 1.0f);
    float distB = apap - d1 - d1 + aa;
    float ubc = tbc * bb - e - e;
    float dBC = distB + tbc * ubc;

    float m3 = fminf(fminf(dAB, dAC), dBC);
    bool inside = (vb >= 0.0f) && (vc >= 0.0f) && (va > 0.0f);
    float dist = inside ? di : m3;

    mind = fminf(mind, dist);
  }
  part[((size_t)b * NS + s) * NP + p] = fmaxf(mind, 0.0f);
}

// ---------------------------------------------------------------------------
// Kernel 3: parallel reduce. 64 blocks (16/batch) x 256 threads; each thread
// owns one point: min over NS split-partials, mask, block-reduce -> bl2.
// ---------------------------------------------------------------------------
__global__ __launch_bounds__(256) void reduce_kernel(
    const float* __restrict__ part, const float* __restrict__ pc,
    float* __restrict__ bl2)
{
  int blk = blockIdx.x;
  int b = blk >> 4;
  int p = (blk & 15) * 256 + threadIdx.x;
  float m = FLT_MAX;
  #pragma unroll
  for (int s = 0; s < NS; ++s)
    m = fminf(m, part[((size_t)b * NS + s) * NP + p]);
  const float* pp = pc + ((size_t)b * NP + p) * 3;
  float x = pp[0], y = pp[1], z = pp[2];
  float msk = ((x != 0.0f) | (y != 0.0f) | (z != 0.0f)) ? 1.0f : 0.0f;
  float sdm = m * msk, sm = msk;
  for (int off = 32; off > 0; off >>= 1) {
    sdm += __shfl_down(sdm, off, 64);
    sm  += __shfl_down(sm,  off, 64);
  }
  __shared__ float s1[4], s2[4];
  int wave = threadIdx.x >> 6, lane = threadIdx.x & 63;
  if (lane == 0) { s1[wave] = sdm; s2[wave] = sm; }
  __syncthreads();
  if (threadIdx.x == 0) {
    bl2[2 * blk]     = s1[0] + s1[1] + s1[2] + s1[3];
    bl2[2 * blk + 1] = s2[0] + s2[1] + s2[2] + s2[3];
  }
}

__global__ void final_kernel(const float* __restrict__ bl2, float* __restrict__ out)
{
  if (threadIdx.x == 0 && blockIdx.x == 0) {
    float acc = 0.0f;
    for (int b = 0; b < NB; ++b) {
      float sdm = 0.0f, sm = 0.0f;
      for (int k = 0; k < 16; ++k) {
        sdm += bl2[2 * (b * 16 + k)];
        sm  += bl2[2 * (b * 16 + k) + 1];
      }
      acc += sdm / fmaxf(sm, 1.0f);
    }
    out[0] = 0.25f * acc;
  }
}

extern "C" void kernel_launch(void* const* d_in, const int* in_sizes, int n_in,
                              void* d_out, int out_size, void* d_ws, size_t ws_size,
                              hipStream_t stream) {
  const float* verts = (const float*)d_in[0];   // (4,3,16,16,16) f32
  const float* pc    = (const float*)d_in[1];   // (4,4096,3) f32
  const int*   faces = (const int*)d_in[2];     // (8192,3) i32
  float* out = (float*)d_out;

  float* tri  = (float*)d_ws;                       // NB*NT*TREC = 655360 floats (2.6 MB)
  float* part = tri  + (size_t)NB * NT * TREC;      // NB*NS*NP = 524288 floats (2 MB)
  float* bl2  = part + (size_t)NB * NS * NP;        // 128 floats

  prep_kernel<<<(NB * NT) / 256, 256, 0, stream>>>(verts, faces, tri);
  dist_kernel<<<NB * NS * 16, 256, 0, stream>>>(tri, pc, part);
  reduce_kernel<<<NB * 16, 256, 0, stream>>>(part, pc, bl2);
  final_kernel<<<1, 64, 0, stream>>>(bl2, out);
}

// Round 3
// 180.244 us; speedup vs baseline: 1.9123x; 1.2492x over previous
//
#include <hip/hip_runtime.h>
#include <math.h>
#include <float.h>

#define NB 4
#define NP 4096     // points (and vertices) per batch
#define NT 8192     // triangles
#define NS 64       // triangle splits
#define TCH (NT/NS) // 128 triangles per split
#define TREC 20     // floats per triangle record (5 x float4)
#define EPSD 1e-12

typedef float f2 __attribute__((ext_vector_type(2)));

__device__ __forceinline__ float sigm(float x) { return 1.0f / (1.0f + expf(-x)); }
__device__ __forceinline__ f2 vmin2(f2 a, f2 b) { return __builtin_elementwise_min(a, b); }
__device__ __forceinline__ f2 vmax2(f2 a, f2 b) { return __builtin_elementwise_max(a, b); }
__device__ __forceinline__ f2 clamp01(f2 x) {
  f2 z; z.x = 0.0f; z.y = 0.0f;
  f2 o; o.x = 1.0f; o.y = 1.0f;
  return vmin2(vmax2(x, z), o);
}

// ---------------------------------------------------------------------------
// Kernel 1: per-(batch,triangle) precompute -> 20-float record:
// [ax ay az abx | aby abz acx acy | acz aa am cc | raa rcc rbb rden | den bb k1 pad]
// Constants in double. den = aa*cc - am^2 (Gram det) is EXACTLY 0 for
// duplicate-index faces -> strict va>0 inside-test excludes them, falling back
// to the edge-segment min (exactly right for degenerate triangles).
// ---------------------------------------------------------------------------
__global__ __launch_bounds__(256) void prep_kernel(
    const float* __restrict__ verts, const int* __restrict__ faces,
    float* __restrict__ tri)
{
  int idx = blockIdx.x * 256 + threadIdx.x;
  if (idx >= NB * NT) return;
  int b = idx >> 13;          // / NT
  int t = idx & (NT - 1);
  int f0 = faces[3 * t + 0], f1 = faces[3 * t + 1], f2i = faces[3 * t + 2];
  const float* vb = verts + (size_t)b * 3 * NP;
  float ax = sigm(vb[f0]),  ay = sigm(vb[NP + f0]),  az = sigm(vb[2 * NP + f0]);
  float bx = sigm(vb[f1]),  by = sigm(vb[NP + f1]),  bz = sigm(vb[2 * NP + f1]);
  float cx = sigm(vb[f2i]), cy = sigm(vb[NP + f2i]), cz = sigm(vb[2 * NP + f2i]);
  float abx = bx - ax, aby = by - ay, abz = bz - az;
  float acx = cx - ax, acy = cy - ay, acz = cz - az;
  double aa = (double)abx * abx + (double)aby * aby + (double)abz * abz;
  double am = (double)abx * acx + (double)aby * acy + (double)abz * acz;
  double cc = (double)acx * acx + (double)acy * acy + (double)acz * acz;
  double den = aa * cc - am * am;       // Gram determinant; 0 iff degenerate
  double bb  = aa - 2.0 * am + cc;      // |bc|^2
  float raa  = (fabs(aa)  < EPSD) ? 1.0f : (float)(1.0 / aa);
  float rcc  = (fabs(cc)  < EPSD) ? 1.0f : (float)(1.0 / cc);
  float rbb  = (fabs(bb)  < EPSD) ? 1.0f : (float)(1.0 / bb);
  float rden = (fabs(den) < EPSD) ? 0.0f : (float)(1.0 / den);
  float* r = tri + (size_t)idx * TREC;
  r[0]  = ax;  r[1]  = ay;  r[2]  = az;
  r[3]  = abx; r[4]  = aby; r[5]  = abz;
  r[6]  = acx; r[7]  = acy; r[8]  = acz;
  r[9]  = (float)aa; r[10] = (float)am; r[11] = (float)cc;
  r[12] = raa; r[13] = rcc; r[14] = rbb; r[15] = rden;
  r[16] = (float)den; r[17] = (float)bb; r[18] = (float)(aa - am); r[19] = 0.0f;
}

// ---------------------------------------------------------------------------
// Kernel 2: hot loop. One thread = TWO points (p and p+256) vs one
// 128-triangle split; all point state is float2 (invites v_pk_fma_f32 /
// v_pk_add_f32 and gives 2 independent dependency chains). Triangle record is
// wave-uniform -> scalar loads. dist = inside ? plane-projection : min over
// 3 edge segments (clamped parameter). Strict va>0 handles degenerates.
// ---------------------------------------------------------------------------
__global__ __launch_bounds__(256) void dist_kernel(
    const float* __restrict__ tri, const float* __restrict__ pc,
    float* __restrict__ part)
{
  int bid  = blockIdx.x;
  int pblk = bid & 7;
  int s    = (bid >> 3) & (NS - 1);
  int b    = bid >> 9;
  int p0   = pblk * 512 + threadIdx.x;   // second point = p0 + 256
  const float* pp0 = pc + ((size_t)b * NP + p0) * 3;
  const float* pp1 = pp0 + 256 * 3;
  f2 px, py, pz;
  px.x = pp0[0]; px.y = pp1[0];
  py.x = pp0[1]; py.y = pp1[1];
  pz.x = pp0[2]; pz.y = pp1[2];

  const float4* __restrict__ R =
      (const float4*)(tri + (size_t)(b * NT + s * TCH) * TREC);
  f2 mind; mind.x = FLT_MAX; mind.y = FLT_MAX;

  #pragma unroll 2
  for (int t = 0; t < TCH; ++t) {
    float4 r0 = R[0], r1 = R[1], r2 = R[2], r3 = R[3], r4 = R[4];
    R += 5;
    float abx = r0.w, aby = r1.x, abz = r1.y;
    float acx = r1.z, acy = r1.w, acz = r2.x;
    float aa = r2.y, am = r2.z, cc = r2.w;
    float raa = r3.x, rcc = r3.y, rbb = r3.z, rden = r3.w;
    float den = r4.x, bb = r4.y, k1 = r4.z;

    f2 apx = px - r0.x, apy = py - r0.y, apz = pz - r0.z;

    f2 d1   = apx * abx + apy * aby + apz * abz;
    f2 d2   = apx * acx + apy * acy + apz * acz;
    f2 apap = apx * apx + apy * apy + apz * apz;

    f2 vb = d1 * cc - d2 * am;
    f2 vc = d2 * aa - d1 * am;
    f2 va = den - vb - vc;

    // interior (plane projection)
    f2 di = apap - (vb * d1 + vc * d2) * rden;

    f2 t2 = d1 + d1;
    f2 tab = clamp01(d1 * raa);
    f2 dAB = apap + tab * (tab * aa - t2);

    f2 t4 = d2 + d2;
    f2 tac = clamp01(d2 * rcc);
    f2 dAC = apap + tac * (tac * cc - t4);

    f2 e = d2 - d1 + k1;
    f2 tbc = clamp01(e * rbb);
    f2 distB = apap - t2 + aa;
    f2 dBC = distB + tbc * (tbc * bb - (e + e));

    f2 m3 = vmin2(vmin2(dAB, dAC), dBC);

    bool in0 = (vb.x >= 0.0f) & (vc.x >= 0.0f) & (va.x > 0.0f);
    bool in1 = (vb.y >= 0.0f) & (vc.y >= 0.0f) & (va.y > 0.0f);
    f2 dist;
    dist.x = in0 ? di.x : m3.x;
    dist.y = in1 ? di.y : m3.y;

    mind = vmin2(mind, dist);
  }
  float* dst = part + ((size_t)b * NS + s) * NP + p0;
  dst[0]   = fmaxf(mind.x, 0.0f);
  dst[256] = fmaxf(mind.y, 0.0f);
}

// ---------------------------------------------------------------------------
// Kernel 3: parallel reduce. 64 blocks (16/batch) x 256 threads; each thread
// owns one point: min over NS split-partials, mask, block-reduce -> bl2.
// ---------------------------------------------------------------------------
__global__ __launch_bounds__(256) void reduce_kernel(
    const float* __restrict__ part, const float* __restrict__ pc,
    float* __restrict__ bl2)
{
  int blk = blockIdx.x;
  int b = blk >> 4;
  int p = (blk & 15) * 256 + threadIdx.x;
  float m = FLT_MAX;
  #pragma unroll
  for (int s = 0; s < NS; ++s)
    m = fminf(m, part[((size_t)b * NS + s) * NP + p]);
  const float* pp = pc + ((size_t)b * NP + p) * 3;
  float x = pp[0], y = pp[1], z = pp[2];
  float msk = ((x != 0.0f) | (y != 0.0f) | (z != 0.0f)) ? 1.0f : 0.0f;
  float sdm = m * msk, sm = msk;
  for (int off = 32; off > 0; off >>= 1) {
    sdm += __shfl_down(sdm, off, 64);
    sm  += __shfl_down(sm,  off, 64);
  }
  __shared__ float s1[4], s2[4];
  int wave = threadIdx.x >> 6, lane = threadIdx.x & 63;
  if (lane == 0) { s1[wave] = sdm; s2[wave] = sm; }
  __syncthreads();
  if (threadIdx.x == 0) {
    bl2[2 * blk]     = s1[0] + s1[1] + s1[2] + s1[3];
    bl2[2 * blk + 1] = s2[0] + s2[1] + s2[2] + s2[3];
  }
}

__global__ void final_kernel(const float* __restrict__ bl2, float* __restrict__ out)
{
  if (threadIdx.x == 0 && blockIdx.x == 0) {
    float acc = 0.0f;
    for (int b = 0; b < NB; ++b) {
      float sdm = 0.0f, sm = 0.0f;
      for (int k = 0; k < 16; ++k) {
        sdm += bl2[2 * (b * 16 + k)];
        sm  += bl2[2 * (b * 16 + k) + 1];
      }
      acc += sdm / fmaxf(sm, 1.0f);
    }
    out[0] = 0.25f * acc;
  }
}

extern "C" void kernel_launch(void* const* d_in, const int* in_sizes, int n_in,
                              void* d_out, int out_size, void* d_ws, size_t ws_size,
                              hipStream_t stream) {
  const float* verts = (const float*)d_in[0];   // (4,3,16,16,16) f32
  const float* pc    = (const float*)d_in[1];   // (4,4096,3) f32
  const int*   faces = (const int*)d_in[2];     // (8192,3) i32
  float* out = (float*)d_out;

  float* tri  = (float*)d_ws;                       // NB*NT*TREC = 655360 floats (2.6 MB)
  float* part = tri  + (size_t)NB * NT * TREC;      // NB*NS*NP = 1048576 floats (4 MB)
  float* bl2  = part + (size_t)NB * NS * NP;        // 128 floats

  prep_kernel<<<(NB * NT) / 256, 256, 0, stream>>>(verts, faces, tri);
  dist_kernel<<<NB * NS * 8, 256, 0, stream>>>(tri, pc, part);
  reduce_kernel<<<NB * 16, 256, 0, stream>>>(part, pc, bl2);
  final_kernel<<<1, 64, 0, stream>>>(bl2, out);
}